// Round 11
// baseline (38.752 us; speedup 1.0000x reference)
//
#include <hip/hip_runtime.h>
#include <cstdint>

constexpr int P   = 32;
constexpr int RES = 256;
constexpr int H   = 480;
constexpr int W   = 640;
#define KMAX 0xFFFFFFFFu

__device__ __forceinline__ uint32_t mono_key(float f) {
    uint32_t b = __float_as_uint(f);
    return (b & 0x80000000u) ? ~b : (b | 0x80000000u);
}
__device__ __forceinline__ float unmono(uint32_t m) {
    uint32_t b = (m & 0x80000000u) ? (m ^ 0x80000000u) : ~m;
    return __uint_as_float(b);
}
__device__ __forceinline__ float h2f(unsigned short u) {
    return (float)__builtin_bit_cast(_Float16, u);
}
__device__ __forceinline__ unsigned short f2h(float f) {
    return __builtin_bit_cast(unsigned short, (_Float16)f);
}

// Blocked-texture address: 4x4-texel blocks, one block = 16 ushort4 = 128 B
// = exactly one cache line. plane base is in ushort4 units (p << 16).
__device__ __forceinline__ int tex_addr(int base, int xx, int yy) {
    return base + ((((yy >> 2) << 6) | (xx >> 2)) << 4) + ((yy & 3) << 2) + (xx & 3);
}

// Repack content (P,4,256,256) f32 -> blocked f16 tex: thread-per-4x4-block.
// Reads: float4-dense per wave; writes: 128 B contiguous per thread.
// Block 0, lanes<32 also build the per-plane constant table.
__global__ __launch_bounds__(256) void prep_repack_kernel(
    const float* __restrict__ content,
    const float* __restrict__ basis, const float* __restrict__ ppos,
    const float* __restrict__ pwh,   const float* __restrict__ camR,
    const float* __restrict__ camT,
    float4* __restrict__ tab, ushort4* __restrict__ tex)
{
    const int tid = blockIdx.x * 256 + threadIdx.x;      // < P*4096 blocks
    const int p   = tid >> 12;
    const int blk = tid & 4095;
    const int by  = blk >> 6, bx = blk & 63;
    const float* src = content + ((size_t)p << 18);
    ushort4* dst = tex + ((size_t)tid << 4);

    #pragma unroll
    for (int dy = 0; dy < 4; ++dy) {
        const int ti = ((by << 2) + dy) * 256 + (bx << 2);
        const float4 c0 = *reinterpret_cast<const float4*>(src + ti);
        const float4 c1 = *reinterpret_cast<const float4*>(src + 65536  + ti);
        const float4 c2 = *reinterpret_cast<const float4*>(src + 131072 + ti);
        const float4 c3 = *reinterpret_cast<const float4*>(src + 196608 + ti);
        ushort4 o;
        o.x = f2h(c0.x); o.y = f2h(c1.x); o.z = f2h(c2.x); o.w = f2h(c3.x);
        dst[(dy << 2) + 0] = o;
        o.x = f2h(c0.y); o.y = f2h(c1.y); o.z = f2h(c2.y); o.w = f2h(c3.y);
        dst[(dy << 2) + 1] = o;
        o.x = f2h(c0.z); o.y = f2h(c1.z); o.z = f2h(c2.z); o.w = f2h(c3.z);
        dst[(dy << 2) + 2] = o;
        o.x = f2h(c0.w); o.y = f2h(c1.w); o.z = f2h(c2.w); o.w = f2h(c3.w);
        dst[(dy << 2) + 3] = o;
    }

    if (blockIdx.x == 0 && threadIdx.x < P) {
        const int q = threadIdx.x;
        const float T0=camT[0],T1=camT[1],T2=camT[2];
        const float cpx = -(camR[0]*T0 + camR[3]*T1 + camR[6]*T2);
        const float cpy = -(camR[1]*T0 + camR[4]*T1 + camR[7]*T2);
        const float cpz = -(camR[2]*T0 + camR[5]*T1 + camR[8]*T2);
        const float* b = basis + 9 * q;
        const float n0 = b[2], n1 = b[5], n2 = b[8];
        const float px = ppos[3*q], py = ppos[3*q+1], pz = ppos[3*q+2];
        const float num = n0*(px-cpx) + n1*(py-cpy) + n2*(pz-cpz);
        const float A0  = (cpx-px)*b[0] + (cpy-py)*b[3] + (cpz-pz)*b[6];
        const float A1  = (cpx-px)*b[1] + (cpy-py)*b[4] + (cpz-pz)*b[7];
        const float hw0 = pwh[2*q]   * 0.5f;
        const float hw1 = pwh[2*q+1] * 0.5f;
        tab[4*q+0] = make_float4(n0, n1, n2, num);
        tab[4*q+1] = make_float4(A0, A1, __int_as_float(q << 16), 0.f);
        tab[4*q+2] = make_float4(b[0], b[3], b[6], 1.0f/hw0);
        tab[4*q+3] = make_float4(b[1], b[4], b[7], 1.0f/hw1);
    }
}

// Cooperative split-plane renderer (R10, passing): 2 waves per 64-px tile,
// wave w owns planes [16w,16w+16); sorted records to LDS; stable 2-list
// merge-composite. This round: blocked tex layout only (tap addressing).
__global__ __launch_bounds__(128) void render_fast(
    const ushort4* __restrict__ tex, const float4* __restrict__ tab,
    const float* __restrict__ camR,  float* __restrict__ out)
{
    __shared__ float4   s_pl[P][3];        // [0]=(A0,A1,base,_) [1]=(b0,rhw0) [2]=(b1,rhw1)
    __shared__ uint32_t s_key[2][16][64];  // sorted depth keys per half-list
    __shared__ uint2    s_c4 [2][16][64];  // packed f16x4 (a,R,G,B)

    const int t    = threadIdx.x;
    const int lane = t & 63;
    const int w    = t >> 6;               // wave id (uniform per wave)

    if (t < P) {
        s_pl[t][0] = tab[4*t+1];
        s_pl[t][1] = tab[4*t+2];
        s_pl[t][2] = tab[4*t+3];
    }
    #pragma unroll
    for (int e = 0; e < 16; ++e) s_key[w][e][lane] = KMAX;
    __syncthreads();

    const int x = blockIdx.x * 16 + (lane & 15);
    const int y = blockIdx.y * 4  + (lane >> 4);
    const float gx = ((float)x + 0.5f) / (float)W * 2.0f - 1.0f;
    const float gy = ((float)y + 0.5f) / (float)H * 2.0f - 1.0f;
    const float dwx = gx*camR[0] + gy*camR[3] + camR[6];
    const float dwy = gx*camR[1] + gy*camR[4] + camR[7];
    const float dwz = gx*camR[2] + gy*camR[5] + camR[8];

    const int pb = __builtin_amdgcn_readfirstlane(w) * 16;   // plane base (scalar)

    // ---- pass 1: this wave's 16 planes ----
    uint32_t key[16];
    #pragma unroll
    for (int p = 0; p < 16; ++p) {
        const float4 c0 = tab[4*(pb+p)+0];
        const float4 c1 = tab[4*(pb+p)+1];
        const float4 c2 = tab[4*(pb+p)+2];
        const float4 c3 = tab[4*(pb+p)+3];
        float den = c0.x*dwx + c0.y*dwy + c0.z*dwz;
        if (fabsf(den) < 1e-6f) den = 1e-6f;
        const float d  = c0.w / den;                 // IEEE divide: exact ordering + depth
        const float B0 = c2.x*dwx + c2.y*dwy + c2.z*dwz;
        const float B1 = c3.x*dwx + c3.y*dwy + c3.z*dwz;
        const float u  = (c1.x + d*B0) * c2.w;
        const float v  = (c1.y + d*B1) * c3.w;
        key[p] = (fabsf(u) <= 1.0f && fabsf(v) <= 1.0f) ? mono_key(d) : KMAX;
    }

    // ---- producer: 2-deep pop/tap/sigmoid, store sorted records to LDS ----
    auto argmin_pop = [&](int& obi) -> uint32_t {
        uint32_t bk = KMAX; int bi = 0;
        #pragma unroll
        for (int i = 0; i < 16; ++i) {
            const bool c = key[i] < bk;              // strict < : stable on ties
            bk = c ? key[i] : bk;
            bi = c ? i : bi;
        }
        #pragma unroll
        for (int i = 0; i < 16; ++i)
            key[i] = (i == bi) ? KMAX : key[i];
        obi = bi;
        return bk;
    };

    struct St { ushort4 t00, t01, t10, t11; float wx, wy; int ix, iy; uint32_t key; };

    auto issue = [&](uint32_t k, int bi) -> St {
        St s;
        s.key = k;
        const bool valid = (k != KMAX);
        const float d = valid ? unmono(k) : 0.0f;    // finite math for idle lanes
        const int g = pb + bi;
        const float4 pA = s_pl[g][0];
        const float4 pB = s_pl[g][1];
        const float4 pC = s_pl[g][2];
        const float B0 = pB.x*dwx + pB.y*dwy + pB.z*dwz;
        const float B1 = pC.x*dwx + pC.y*dwy + pC.z*dwz;
        const float u  = (pA.x + d*B0) * pB.w;
        const float v  = (pA.y + d*B1) * pC.w;
        const float fx = (u + 1.0f) * 128.0f - 0.5f;
        const float fy = (v + 1.0f) * 128.0f - 0.5f;
        const float x0f = floorf(fx), y0f = floorf(fy);
        s.wx = fx - x0f; s.wy = fy - y0f;
        s.ix = (int)x0f; s.iy = (int)y0f;
        const int x0c = min(max(s.ix,     0), RES-1);
        const int x1c = min(max(s.ix + 1, 0), RES-1);
        const int y0c = min(max(s.iy,     0), RES-1);
        const int y1c = min(max(s.iy + 1, 0), RES-1);
        const int base = __float_as_int(pA.z);       // g << 16
        s.t00 = tex[tex_addr(base, x0c, y0c)];
        s.t01 = tex[tex_addr(base, x1c, y0c)];
        s.t10 = tex[tex_addr(base, x0c, y1c)];
        s.t11 = tex[tex_addr(base, x1c, y1c)];
        return s;
    };

    auto store = [&](const St& s, int e) {
        if (s.key == KMAX) return;                   // lane exhausted: slot stays KMAX
        ushort4 t00 = s.t00, t01 = s.t01, t10 = s.t10, t11 = s.t11;
        const bool mx0 = (uint32_t)s.ix       < (uint32_t)RES;
        const bool mx1 = (uint32_t)(s.ix + 1) < (uint32_t)RES;
        const bool my0 = (uint32_t)s.iy       < (uint32_t)RES;
        const bool my1 = (uint32_t)(s.iy + 1) < (uint32_t)RES;
        if (!(mx0 && my0)) { t00.x = t00.y = t00.z = t00.w = 0; }
        if (!(mx1 && my0)) { t01.x = t01.y = t01.z = t01.w = 0; }
        if (!(mx0 && my1)) { t10.x = t10.y = t10.z = t10.w = 0; }
        if (!(mx1 && my1)) { t11.x = t11.y = t11.z = t11.w = 0; }
        const float omwx = 1.0f - s.wx, omwy = 1.0f - s.wy;
        const unsigned short* q00 = (const unsigned short*)&t00;
        const unsigned short* q01 = (const unsigned short*)&t01;
        const unsigned short* q10 = (const unsigned short*)&t10;
        const unsigned short* q11 = (const unsigned short*)&t11;
        float c4[4];
        #pragma unroll
        for (int c = 0; c < 4; ++c) {
            const float top = h2f(q00[c]) * omwx + h2f(q01[c]) * s.wx;
            const float bot = h2f(q10[c]) * omwx + h2f(q11[c]) * s.wx;
            const float raw = top * omwy + bot * s.wy;
            c4[c] = __builtin_amdgcn_rcpf(1.0f + __expf(-raw));   // sigmoid
        }
        s_key[w][e][lane] = s.key;
        s_c4[w][e][lane]  = make_uint2(
            (uint32_t)f2h(c4[0]) | ((uint32_t)f2h(c4[1]) << 16),
            (uint32_t)f2h(c4[2]) | ((uint32_t)f2h(c4[3]) << 16));
    };

    int e = 0;
    int cbi; uint32_t ck = argmin_pop(cbi);
    if (__ballot(ck != KMAX) != 0ull) {
        St cur = issue(ck, cbi);
        for (;;) {
            int nbi; const uint32_t nk = argmin_pop(nbi);
            const bool more = (__ballot(nk != KMAX) != 0ull);
            St nxt;
            if (more) nxt = issue(nk, nbi);          // loads in flight across store
            store(cur, e); ++e;
            if (!more) break;
            cur = nxt;
        }
    }
    __syncthreads();

    // ---- merge-composite: each wave's low 32 lanes handle 32 pixels ----
    const int q  = w * 32 + (t & 31);                // pixel index in tile
    const bool act = (t & 63) < 32;
    int i0 = 0, i1 = 0;
    uint32_t k0 = act ? s_key[0][0][q] : KMAX;
    uint32_t k1 = act ? s_key[1][0][q] : KMAX;
    float aR = 0.f, aG = 0.f, aB = 0.f, aD = 0.f, tr = 1.f;

    while (__ballot(k0 != KMAX || k1 != KMAX) != 0ull) {
        const bool take0 = (k0 <= k1);               // ties -> list 0 (lower plane idx)
        const uint32_t k = take0 ? k0 : k1;
        const bool valid = (k != KMAX);
        const int  li = (take0 ? i0 : i1) & 15;
        const uint2 cp = s_c4[take0 ? 0 : 1][li][q];
        if (take0) { ++i0; k0 = (i0 < 16) ? s_key[0][i0][q] : KMAX; }
        else       { ++i1; k1 = (i1 < 16) ? s_key[1][i1][q] : KMAX; }
        // gate EVERY decoded value: un-stored s_c4 slots hold garbage bits
        // that can decode to NaN, and NaN*0 = NaN (the R9 failure).
        const float a  = valid ? h2f((unsigned short)(cp.x & 0xFFFFu)) : 0.0f;
        const float cR = valid ? h2f((unsigned short)(cp.x >> 16))     : 0.0f;
        const float cG = valid ? h2f((unsigned short)(cp.y & 0xFFFFu)) : 0.0f;
        const float cB = valid ? h2f((unsigned short)(cp.y >> 16))     : 0.0f;
        const float d  = valid ? unmono(k) : 0.0f;
        const float wgt = a * tr;
        aD += d  * wgt;
        aR += cR * wgt;
        aG += cG * wgt;
        aB += cB * wgt;
        tr *= (1.0f - a);
    }

    if (act) {
        const int px = blockIdx.x * 16 + (q & 15);
        const int py = blockIdx.y * 4  + (q >> 4);
        float4 res; res.x = aR; res.y = aG; res.z = aB; res.w = aD;
        *reinterpret_cast<float4*>(out + (py * W + px) * 4) = res;
    }
}

// ---- fallback (ws too small): self-contained f32 path, round-1 proven ----
__global__ __launch_bounds__(256) void render_ref(
    const float* __restrict__ content, const float* __restrict__ basis,
    const float* __restrict__ ppos,    const float* __restrict__ pwh,
    const float* __restrict__ camR,    const float* __restrict__ camT,
    float* __restrict__ out)
{
    __shared__ float s_pl[P][20];
    const int t = threadIdx.x;
    const int x = blockIdx.x * 16 + (t & 15);
    const int y = blockIdx.y * 16 + (t >> 4);
    if (t < P) {
        const float* b = basis + t * 9;
        s_pl[t][0] = b[0]; s_pl[t][1] = b[3]; s_pl[t][2] = b[6];
        s_pl[t][3] = b[1]; s_pl[t][4] = b[4]; s_pl[t][5] = b[7];
        s_pl[t][6] = ppos[t*3+0]; s_pl[t][7] = ppos[t*3+1]; s_pl[t][8] = ppos[t*3+2];
        s_pl[t][9] = pwh[t*2+0] * 0.5f; s_pl[t][10] = pwh[t*2+1] * 0.5f;
    }
    __syncthreads();
    const float T0=camT[0],T1=camT[1],T2=camT[2];
    const float cpx = -(camR[0]*T0 + camR[3]*T1 + camR[6]*T2);
    const float cpy = -(camR[1]*T0 + camR[4]*T1 + camR[7]*T2);
    const float cpz = -(camR[2]*T0 + camR[5]*T1 + camR[8]*T2);
    const float gx = ((float)x + 0.5f) / (float)W * 2.0f - 1.0f;
    const float gy = ((float)y + 0.5f) / (float)H * 2.0f - 1.0f;
    const float dwx = gx*camR[0] + gy*camR[3] + camR[6];
    const float dwy = gx*camR[1] + gy*camR[4] + camR[7];
    const float dwz = gx*camR[2] + gy*camR[5] + camR[8];
    uint32_t key[P];
    #pragma unroll
    for (int p = 0; p < P; ++p) {
        const float b00=basis[p*9+0], b01=basis[p*9+1], n0=basis[p*9+2];
        const float b10=basis[p*9+3], b11=basis[p*9+4], n1=basis[p*9+5];
        const float b20=basis[p*9+6], b21=basis[p*9+7], n2=basis[p*9+8];
        const float px=ppos[p*3+0], py=ppos[p*3+1], pz=ppos[p*3+2];
        const float hw0=pwh[p*2+0]*0.5f, hw1=pwh[p*2+1]*0.5f;
        const float num = n0*(px-cpx) + n1*(py-cpy) + n2*(pz-cpz);
        float den = n0*dwx + n1*dwy + n2*dwz;
        if (fabsf(den) < 1e-6f) den = 1e-6f;
        const float depth = num / den;
        const float ox = cpx + depth*dwx - px;
        const float oy = cpy + depth*dwy - py;
        const float oz = cpz + depth*dwz - pz;
        const float u = (ox*b00 + oy*b10 + oz*b20) / hw0;
        const float v = (ox*b01 + oy*b11 + oz*b21) / hw1;
        key[p] = (fabsf(u) <= 1.0f && fabsf(v) <= 1.0f) ? mono_key(depth) : KMAX;
    }
    float aR=0.f,aG=0.f,aB=0.f,aD=0.f,tr=1.f;
    #pragma unroll 1
    for (int it = 0; it < P; ++it) {
        uint32_t bk = KMAX; int bi = 0;
        #pragma unroll
        for (int i = 0; i < P; ++i) {
            const bool c = key[i] < bk;
            bk = c ? key[i] : bk; bi = c ? i : bi;
        }
        if (bk == KMAX) break;
        #pragma unroll
        for (int i = 0; i < P; ++i) key[i] = (i == bi) ? KMAX : key[i];
        const float depth = unmono(bk);
        const float* pl = s_pl[bi];
        const float ox = cpx + depth*dwx - pl[6];
        const float oy = cpy + depth*dwy - pl[7];
        const float oz = cpz + depth*dwz - pl[8];
        const float u = (ox*pl[0] + oy*pl[1] + oz*pl[2]) / pl[9];
        const float v = (ox*pl[3] + oy*pl[4] + oz*pl[5]) / pl[10];
        const float fx = (u + 1.0f) * 128.0f - 0.5f;
        const float fy = (v + 1.0f) * 128.0f - 0.5f;
        const float x0f = floorf(fx), y0f = floorf(fy);
        const float wx = fx - x0f, wy = fy - y0f;
        const int ix = (int)x0f, iy = (int)y0f;
        const int x0c = min(max(ix,0),RES-1), x1c = min(max(ix+1,0),RES-1);
        const int y0c = min(max(iy,0),RES-1), y1c = min(max(iy+1,0),RES-1);
        const float m00 = ((uint32_t)ix<(uint32_t)RES && (uint32_t)iy<(uint32_t)RES) ? 1.f:0.f;
        const float m01 = ((uint32_t)(ix+1)<(uint32_t)RES && (uint32_t)iy<(uint32_t)RES) ? 1.f:0.f;
        const float m10 = ((uint32_t)ix<(uint32_t)RES && (uint32_t)(iy+1)<(uint32_t)RES) ? 1.f:0.f;
        const float m11 = ((uint32_t)(ix+1)<(uint32_t)RES && (uint32_t)(iy+1)<(uint32_t)RES) ? 1.f:0.f;
        const int o00=y0c*RES+x0c, o01=y0c*RES+x1c, o10=y1c*RES+x0c, o11=y1c*RES+x1c;
        const float* pc = content + ((size_t)bi << 18);
        float c4[4];
        #pragma unroll
        for (int c = 0; c < 4; ++c) {
            const float* ic = pc + (c << 16);
            const float v00 = ic[o00]*m00, v01 = ic[o01]*m01;
            const float v10 = ic[o10]*m10, v11 = ic[o11]*m11;
            const float top = v00*(1.f-wx) + v01*wx;
            const float bot = v10*(1.f-wx) + v11*wx;
            const float raw = top*(1.f-wy) + bot*wy;
            c4[c] = 1.0f / (1.0f + __expf(-raw));
        }
        const float wgt = c4[0]*tr;
        aD += depth*wgt; aR += c4[1]*wgt; aG += c4[2]*wgt; aB += c4[3]*wgt;
        tr *= (1.0f - c4[0]);
    }
    const int o = (y * W + x) * 4;
    float4 res; res.x=aR; res.y=aG; res.z=aB; res.w=aD;
    *reinterpret_cast<float4*>(out + o) = res;
}

extern "C" void kernel_launch(void* const* d_in, const int* in_sizes, int n_in,
                              void* d_out, int out_size, void* d_ws, size_t ws_size,
                              hipStream_t stream) {
    const float* content = (const float*)d_in[0];
    const float* basis   = (const float*)d_in[1];
    const float* ppos    = (const float*)d_in[2];
    const float* pwh     = (const float*)d_in[3];
    const float* camR    = (const float*)d_in[4];
    const float* camT    = (const float*)d_in[5];

    const size_t TAB_BYTES = 2048;                               // 32*4*16
    const size_t need = TAB_BYTES + (size_t)P * 65536 * sizeof(ushort4);

    if (ws_size >= need) {
        float4*  tab = (float4*)d_ws;
        ushort4* tex = (ushort4*)((char*)d_ws + TAB_BYTES);
        prep_repack_kernel<<<P * 4096 / 256, 256, 0, stream>>>(
            content, basis, ppos, pwh, camR, camT, tab, tex);
        render_fast<<<dim3(W / 16, H / 4), dim3(128), 0, stream>>>(
            tex, tab, camR, (float*)d_out);
    } else {
        dim3 grid(W / 16, H / 16);
        render_ref<<<grid, dim3(256), 0, stream>>>(
            content, basis, ppos, pwh, camR, camT, (float*)d_out);
    }
}

// Round 12
// 35.559 us; speedup vs baseline: 1.0898x; 1.0898x over previous
//
#include <hip/hip_runtime.h>
#include <cstdint>

constexpr int P   = 32;
constexpr int RES = 256;
constexpr int H   = 480;
constexpr int W   = 640;
#define KMAX 0xFFFFFFFFu

__device__ __forceinline__ uint32_t mono_key(float f) {
    uint32_t b = __float_as_uint(f);
    return (b & 0x80000000u) ? ~b : (b | 0x80000000u);
}
__device__ __forceinline__ float unmono(uint32_t m) {
    uint32_t b = (m & 0x80000000u) ? (m ^ 0x80000000u) : ~m;
    return __uint_as_float(b);
}
__device__ __forceinline__ float h2f(unsigned short u) {
    return (float)__builtin_bit_cast(_Float16, u);
}
__device__ __forceinline__ unsigned short f2h(float f) {
    return __builtin_bit_cast(unsigned short, (_Float16)f);
}

// Fused: repack content (P,4,256,256) f32 -> tex (P,256,256) ushort4(f16)
//        + block 0, lanes<32 build the per-plane constant table.
__global__ __launch_bounds__(256) void prep_repack_kernel(
    const float* __restrict__ content,
    const float* __restrict__ basis, const float* __restrict__ ppos,
    const float* __restrict__ pwh,   const float* __restrict__ camR,
    const float* __restrict__ camT,
    float4* __restrict__ tab, ushort4* __restrict__ tex)
{
    const int tid = blockIdx.x * 256 + threadIdx.x;      // < P*65536
    const float* src = content + (((size_t)(tid >> 16)) << 18) + (tid & 65535);
    ushort4 o;
    o.x = f2h(src[0]);
    o.y = f2h(src[65536]);
    o.z = f2h(src[131072]);
    o.w = f2h(src[196608]);
    tex[tid] = o;

    if (blockIdx.x == 0 && threadIdx.x < P) {
        const int p = threadIdx.x;
        const float T0=camT[0],T1=camT[1],T2=camT[2];
        const float cpx = -(camR[0]*T0 + camR[3]*T1 + camR[6]*T2);
        const float cpy = -(camR[1]*T0 + camR[4]*T1 + camR[7]*T2);
        const float cpz = -(camR[2]*T0 + camR[5]*T1 + camR[8]*T2);
        const float* b = basis + 9 * p;
        const float n0 = b[2], n1 = b[5], n2 = b[8];
        const float px = ppos[3*p], py = ppos[3*p+1], pz = ppos[3*p+2];
        const float num = n0*(px-cpx) + n1*(py-cpy) + n2*(pz-cpz);
        const float A0  = (cpx-px)*b[0] + (cpy-py)*b[3] + (cpz-pz)*b[6];
        const float A1  = (cpx-px)*b[1] + (cpy-py)*b[4] + (cpz-pz)*b[7];
        const float hw0 = pwh[2*p]   * 0.5f;
        const float hw1 = pwh[2*p+1] * 0.5f;
        tab[4*p+0] = make_float4(n0, n1, n2, num);
        tab[4*p+1] = make_float4(A0, A1, __int_as_float(p << 16), 0.f);
        tab[4*p+2] = make_float4(b[0], b[3], b[6], 1.0f/hw0);
        tab[4*p+3] = make_float4(b[1], b[4], b[7], 1.0f/hw1);
    }
}

// Cooperative split-plane renderer (R10, best known: 35.7 us total):
// 128 threads = 2 waves, both mapped to the SAME 64-pixel (16x4) tile.
// Wave w handles planes [16w, 16w+16): pass-1, sorted argmin-pop (16
// entries), taps + sigmoid, writing per-hit (key, f16x4 c4) records to LDS
// as prefix-packed sorted lists. After one sync, each wave's low 32 lanes
// stable-merge the two sorted lists and composite (ties -> list 0 = lower
// plane idx = reference stable order). All decoded merge values are gated
// by `valid` (un-stored s_c4 slots hold garbage; NaN*0=NaN -- R9 failure).
__global__ __launch_bounds__(128) void render_fast(
    const ushort4* __restrict__ tex, const float4* __restrict__ tab,
    const float* __restrict__ camR,  float* __restrict__ out)
{
    __shared__ float4   s_pl[P][3];        // [0]=(A0,A1,base,_) [1]=(b0,rhw0) [2]=(b1,rhw1)
    __shared__ uint32_t s_key[2][16][64];  // sorted depth keys per half-list
    __shared__ uint2    s_c4 [2][16][64];  // packed f16x4 (a,R,G,B)

    const int t    = threadIdx.x;
    const int lane = t & 63;
    const int w    = t >> 6;               // wave id (uniform per wave)

    if (t < P) {
        s_pl[t][0] = tab[4*t+1];
        s_pl[t][1] = tab[4*t+2];
        s_pl[t][2] = tab[4*t+3];
    }
    #pragma unroll
    for (int e = 0; e < 16; ++e) s_key[w][e][lane] = KMAX;
    __syncthreads();

    const int x = blockIdx.x * 16 + (lane & 15);
    const int y = blockIdx.y * 4  + (lane >> 4);
    const float gx = ((float)x + 0.5f) / (float)W * 2.0f - 1.0f;
    const float gy = ((float)y + 0.5f) / (float)H * 2.0f - 1.0f;
    const float dwx = gx*camR[0] + gy*camR[3] + camR[6];
    const float dwy = gx*camR[1] + gy*camR[4] + camR[7];
    const float dwz = gx*camR[2] + gy*camR[5] + camR[8];

    const int pb = __builtin_amdgcn_readfirstlane(w) * 16;   // plane base (scalar)

    // ---- pass 1: this wave's 16 planes ----
    uint32_t key[16];
    #pragma unroll
    for (int p = 0; p < 16; ++p) {
        const float4 c0 = tab[4*(pb+p)+0];
        const float4 c1 = tab[4*(pb+p)+1];
        const float4 c2 = tab[4*(pb+p)+2];
        const float4 c3 = tab[4*(pb+p)+3];
        float den = c0.x*dwx + c0.y*dwy + c0.z*dwz;
        if (fabsf(den) < 1e-6f) den = 1e-6f;
        const float d  = c0.w / den;                 // IEEE divide: exact ordering + depth
        const float B0 = c2.x*dwx + c2.y*dwy + c2.z*dwz;
        const float B1 = c3.x*dwx + c3.y*dwy + c3.z*dwz;
        const float u  = (c1.x + d*B0) * c2.w;
        const float v  = (c1.y + d*B1) * c3.w;
        key[p] = (fabsf(u) <= 1.0f && fabsf(v) <= 1.0f) ? mono_key(d) : KMAX;
    }

    // ---- producer: 2-deep pop/tap/sigmoid, store sorted records to LDS ----
    auto argmin_pop = [&](int& obi) -> uint32_t {
        uint32_t bk = KMAX; int bi = 0;
        #pragma unroll
        for (int i = 0; i < 16; ++i) {
            const bool c = key[i] < bk;              // strict < : stable on ties
            bk = c ? key[i] : bk;
            bi = c ? i : bi;
        }
        #pragma unroll
        for (int i = 0; i < 16; ++i)
            key[i] = (i == bi) ? KMAX : key[i];
        obi = bi;
        return bk;
    };

    struct St { ushort4 t00, t01, t10, t11; float wx, wy; int ix, iy; uint32_t key; };

    auto issue = [&](uint32_t k, int bi) -> St {
        St s;
        s.key = k;
        const bool valid = (k != KMAX);
        const float d = valid ? unmono(k) : 0.0f;    // finite math for idle lanes
        const int g = pb + bi;
        const float4 pA = s_pl[g][0];
        const float4 pB = s_pl[g][1];
        const float4 pC = s_pl[g][2];
        const float B0 = pB.x*dwx + pB.y*dwy + pB.z*dwz;
        const float B1 = pC.x*dwx + pC.y*dwy + pC.z*dwz;
        const float u  = (pA.x + d*B0) * pB.w;
        const float v  = (pA.y + d*B1) * pC.w;
        const float fx = (u + 1.0f) * 128.0f - 0.5f;
        const float fy = (v + 1.0f) * 128.0f - 0.5f;
        const float x0f = floorf(fx), y0f = floorf(fy);
        s.wx = fx - x0f; s.wy = fy - y0f;
        s.ix = (int)x0f; s.iy = (int)y0f;
        const int x0c = min(max(s.ix,     0), RES-1);
        const int x1c = min(max(s.ix + 1, 0), RES-1);
        const int y0c = min(max(s.iy,     0), RES-1);
        const int y1c = min(max(s.iy + 1, 0), RES-1);
        const int base = __float_as_int(pA.z);       // g << 16
        const int r0 = base + (y0c << 8), r1 = base + (y1c << 8);
        s.t00 = tex[r0 + x0c]; s.t01 = tex[r0 + x1c];
        s.t10 = tex[r1 + x0c]; s.t11 = tex[r1 + x1c];
        return s;
    };

    auto store = [&](const St& s, int e) {
        if (s.key == KMAX) return;                   // lane exhausted: slot stays KMAX
        ushort4 t00 = s.t00, t01 = s.t01, t10 = s.t10, t11 = s.t11;
        const bool mx0 = (uint32_t)s.ix       < (uint32_t)RES;
        const bool mx1 = (uint32_t)(s.ix + 1) < (uint32_t)RES;
        const bool my0 = (uint32_t)s.iy       < (uint32_t)RES;
        const bool my1 = (uint32_t)(s.iy + 1) < (uint32_t)RES;
        if (!(mx0 && my0)) { t00.x = t00.y = t00.z = t00.w = 0; }
        if (!(mx1 && my0)) { t01.x = t01.y = t01.z = t01.w = 0; }
        if (!(mx0 && my1)) { t10.x = t10.y = t10.z = t10.w = 0; }
        if (!(mx1 && my1)) { t11.x = t11.y = t11.z = t11.w = 0; }
        const float omwx = 1.0f - s.wx, omwy = 1.0f - s.wy;
        const unsigned short* q00 = (const unsigned short*)&t00;
        const unsigned short* q01 = (const unsigned short*)&t01;
        const unsigned short* q10 = (const unsigned short*)&t10;
        const unsigned short* q11 = (const unsigned short*)&t11;
        float c4[4];
        #pragma unroll
        for (int c = 0; c < 4; ++c) {
            const float top = h2f(q00[c]) * omwx + h2f(q01[c]) * s.wx;
            const float bot = h2f(q10[c]) * omwx + h2f(q11[c]) * s.wx;
            const float raw = top * omwy + bot * s.wy;
            c4[c] = __builtin_amdgcn_rcpf(1.0f + __expf(-raw));   // sigmoid
        }
        s_key[w][e][lane] = s.key;
        s_c4[w][e][lane]  = make_uint2(
            (uint32_t)f2h(c4[0]) | ((uint32_t)f2h(c4[1]) << 16),
            (uint32_t)f2h(c4[2]) | ((uint32_t)f2h(c4[3]) << 16));
    };

    int e = 0;
    int cbi; uint32_t ck = argmin_pop(cbi);
    if (__ballot(ck != KMAX) != 0ull) {
        St cur = issue(ck, cbi);
        for (;;) {
            int nbi; const uint32_t nk = argmin_pop(nbi);
            const bool more = (__ballot(nk != KMAX) != 0ull);
            St nxt;
            if (more) nxt = issue(nk, nbi);          // loads in flight across store
            store(cur, e); ++e;
            if (!more) break;
            cur = nxt;
        }
    }
    __syncthreads();

    // ---- merge-composite: each wave's low 32 lanes handle 32 pixels ----
    const int q  = w * 32 + (t & 31);                // pixel index in tile
    const bool act = (t & 63) < 32;
    int i0 = 0, i1 = 0;
    uint32_t k0 = act ? s_key[0][0][q] : KMAX;
    uint32_t k1 = act ? s_key[1][0][q] : KMAX;
    float aR = 0.f, aG = 0.f, aB = 0.f, aD = 0.f, tr = 1.f;

    while (__ballot(k0 != KMAX || k1 != KMAX) != 0ull) {
        const bool take0 = (k0 <= k1);               // ties -> list 0 (lower plane idx)
        const uint32_t k = take0 ? k0 : k1;
        const bool valid = (k != KMAX);
        const int  li = (take0 ? i0 : i1) & 15;
        const uint2 cp = s_c4[take0 ? 0 : 1][li][q];
        if (take0) { ++i0; k0 = (i0 < 16) ? s_key[0][i0][q] : KMAX; }
        else       { ++i1; k1 = (i1 < 16) ? s_key[1][i1][q] : KMAX; }
        // gate EVERY decoded value: un-stored s_c4 slots hold garbage bits
        // that can decode to NaN, and NaN*0 = NaN (the R9 failure).
        const float a  = valid ? h2f((unsigned short)(cp.x & 0xFFFFu)) : 0.0f;
        const float cR = valid ? h2f((unsigned short)(cp.x >> 16))     : 0.0f;
        const float cG = valid ? h2f((unsigned short)(cp.y & 0xFFFFu)) : 0.0f;
        const float cB = valid ? h2f((unsigned short)(cp.y >> 16))     : 0.0f;
        const float d  = valid ? unmono(k) : 0.0f;
        const float wgt = a * tr;
        aD += d  * wgt;
        aR += cR * wgt;
        aG += cG * wgt;
        aB += cB * wgt;
        tr *= (1.0f - a);
    }

    if (act) {
        const int px = blockIdx.x * 16 + (q & 15);
        const int py = blockIdx.y * 4  + (q >> 4);
        float4 res; res.x = aR; res.y = aG; res.z = aB; res.w = aD;
        *reinterpret_cast<float4*>(out + (py * W + px) * 4) = res;
    }
}

// ---- fallback (ws too small): self-contained f32 path, round-1 proven ----
__global__ __launch_bounds__(256) void render_ref(
    const float* __restrict__ content, const float* __restrict__ basis,
    const float* __restrict__ ppos,    const float* __restrict__ pwh,
    const float* __restrict__ camR,    const float* __restrict__ camT,
    float* __restrict__ out)
{
    __shared__ float s_pl[P][20];
    const int t = threadIdx.x;
    const int x = blockIdx.x * 16 + (t & 15);
    const int y = blockIdx.y * 16 + (t >> 4);
    if (t < P) {
        const float* b = basis + t * 9;
        s_pl[t][0] = b[0]; s_pl[t][1] = b[3]; s_pl[t][2] = b[6];
        s_pl[t][3] = b[1]; s_pl[t][4] = b[4]; s_pl[t][5] = b[7];
        s_pl[t][6] = ppos[t*3+0]; s_pl[t][7] = ppos[t*3+1]; s_pl[t][8] = ppos[t*3+2];
        s_pl[t][9] = pwh[t*2+0] * 0.5f; s_pl[t][10] = pwh[t*2+1] * 0.5f;
    }
    __syncthreads();
    const float T0=camT[0],T1=camT[1],T2=camT[2];
    const float cpx = -(camR[0]*T0 + camR[3]*T1 + camR[6]*T2);
    const float cpy = -(camR[1]*T0 + camR[4]*T1 + camR[7]*T2);
    const float cpz = -(camR[2]*T0 + camR[5]*T1 + camR[8]*T2);
    const float gx = ((float)x + 0.5f) / (float)W * 2.0f - 1.0f;
    const float gy = ((float)y + 0.5f) / (float)H * 2.0f - 1.0f;
    const float dwx = gx*camR[0] + gy*camR[3] + camR[6];
    const float dwy = gx*camR[1] + gy*camR[4] + camR[7];
    const float dwz = gx*camR[2] + gy*camR[5] + camR[8];
    uint32_t key[P];
    #pragma unroll
    for (int p = 0; p < P; ++p) {
        const float b00=basis[p*9+0], b01=basis[p*9+1], n0=basis[p*9+2];
        const float b10=basis[p*9+3], b11=basis[p*9+4], n1=basis[p*9+5];
        const float b20=basis[p*9+6], b21=basis[p*9+7], n2=basis[p*9+8];
        const float px=ppos[p*3+0], py=ppos[p*3+1], pz=ppos[p*3+2];
        const float hw0=pwh[p*2+0]*0.5f, hw1=pwh[p*2+1]*0.5f;
        const float num = n0*(px-cpx) + n1*(py-cpy) + n2*(pz-cpz);
        float den = n0*dwx + n1*dwy + n2*dwz;
        if (fabsf(den) < 1e-6f) den = 1e-6f;
        const float depth = num / den;
        const float ox = cpx + depth*dwx - px;
        const float oy = cpy + depth*dwy - py;
        const float oz = cpz + depth*dwz - pz;
        const float u = (ox*b00 + oy*b10 + oz*b20) / hw0;
        const float v = (ox*b01 + oy*b11 + oz*b21) / hw1;
        key[p] = (fabsf(u) <= 1.0f && fabsf(v) <= 1.0f) ? mono_key(depth) : KMAX;
    }
    float aR=0.f,aG=0.f,aB=0.f,aD=0.f,tr=1.f;
    #pragma unroll 1
    for (int it = 0; it < P; ++it) {
        uint32_t bk = KMAX; int bi = 0;
        #pragma unroll
        for (int i = 0; i < P; ++i) {
            const bool c = key[i] < bk;
            bk = c ? key[i] : bk; bi = c ? i : bi;
        }
        if (bk == KMAX) break;
        #pragma unroll
        for (int i = 0; i < P; ++i) key[i] = (i == bi) ? KMAX : key[i];
        const float depth = unmono(bk);
        const float* pl = s_pl[bi];
        const float ox = cpx + depth*dwx - pl[6];
        const float oy = cpy + depth*dwy - pl[7];
        const float oz = cpz + depth*dwz - pl[8];
        const float u = (ox*pl[0] + oy*pl[1] + oz*pl[2]) / pl[9];
        const float v = (ox*pl[3] + oy*pl[4] + oz*pl[5]) / pl[10];
        const float fx = (u + 1.0f) * 128.0f - 0.5f;
        const float fy = (v + 1.0f) * 128.0f - 0.5f;
        const float x0f = floorf(fx), y0f = floorf(fy);
        const float wx = fx - x0f, wy = fy - y0f;
        const int ix = (int)x0f, iy = (int)y0f;
        const int x0c = min(max(ix,0),RES-1), x1c = min(max(ix+1,0),RES-1);
        const int y0c = min(max(iy,0),RES-1), y1c = min(max(iy+1,0),RES-1);
        const float m00 = ((uint32_t)ix<(uint32_t)RES && (uint32_t)iy<(uint32_t)RES) ? 1.f:0.f;
        const float m01 = ((uint32_t)(ix+1)<(uint32_t)RES && (uint32_t)iy<(uint32_t)RES) ? 1.f:0.f;
        const float m10 = ((uint32_t)ix<(uint32_t)RES && (uint32_t)(iy+1)<(uint32_t)RES) ? 1.f:0.f;
        const float m11 = ((uint32_t)(ix+1)<(uint32_t)RES && (uint32_t)(iy+1)<(uint32_t)RES) ? 1.f:0.f;
        const int o00=y0c*RES+x0c, o01=y0c*RES+x1c, o10=y1c*RES+x0c, o11=y1c*RES+x1c;
        const float* pc = content + ((size_t)bi << 18);
        float c4[4];
        #pragma unroll
        for (int c = 0; c < 4; ++c) {
            const float* ic = pc + (c << 16);
            const float v00 = ic[o00]*m00, v01 = ic[o01]*m01;
            const float v10 = ic[o10]*m10, v11 = ic[o11]*m11;
            const float top = v00*(1.f-wx) + v01*wx;
            const float bot = v10*(1.f-wx) + v11*wx;
            const float raw = top*(1.f-wy) + bot*wy;
            c4[c] = 1.0f / (1.0f + __expf(-raw));
        }
        const float wgt = c4[0]*tr;
        aD += depth*wgt; aR += c4[1]*wgt; aG += c4[2]*wgt; aB += c4[3]*wgt;
        tr *= (1.0f - c4[0]);
    }
    const int o = (y * W + x) * 4;
    float4 res; res.x=aR; res.y=aG; res.z=aB; res.w=aD;
    *reinterpret_cast<float4*>(out + o) = res;
}

extern "C" void kernel_launch(void* const* d_in, const int* in_sizes, int n_in,
                              void* d_out, int out_size, void* d_ws, size_t ws_size,
                              hipStream_t stream) {
    const float* content = (const float*)d_in[0];
    const float* basis   = (const float*)d_in[1];
    const float* ppos    = (const float*)d_in[2];
    const float* pwh     = (const float*)d_in[3];
    const float* camR    = (const float*)d_in[4];
    const float* camT    = (const float*)d_in[5];

    const size_t TAB_BYTES = 2048;                               // 32*4*16
    const size_t need = TAB_BYTES + (size_t)P * 65536 * sizeof(ushort4);

    if (ws_size >= need) {
        float4*  tab = (float4*)d_ws;
        ushort4* tex = (ushort4*)((char*)d_ws + TAB_BYTES);
        prep_repack_kernel<<<P * 65536 / 256, 256, 0, stream>>>(
            content, basis, ppos, pwh, camR, camT, tab, tex);
        render_fast<<<dim3(W / 16, H / 4), dim3(128), 0, stream>>>(
            tex, tab, camR, (float*)d_out);
    } else {
        dim3 grid(W / 16, H / 16);
        render_ref<<<grid, dim3(256), 0, stream>>>(
            content, basis, ppos, pwh, camR, camT, (float*)d_out);
    }
}